// Round 1
// baseline (113.406 us; speedup 1.0000x reference)
//
#include <hip/hip_runtime.h>

// Problem constants: B=4096 rows, C=4096 channels, M*S=4096 assignment slots.
// Algebraic collapse of the reference:
//   out[b,c] = count[b] * x[b,c],  count[b] = #{(m,s): assignments[m,s]==b}
//   (padding -1 never matches a row index >= 0)
//
// Two-dispatch structure:
//   1) count_kernel: 64 blocks, each owns a 64-row bin range; scans the 16 KB
//      assignments array (L2-resident broadcast) and histograms into LDS,
//      then writes scale[4096] (float) to workspace. ~2 us.
//   2) scale_kernel: pure stream — one uniform scale load per block, then
//      load-mul-store of one 16 KB row per block. No barriers, no LDS, no
//      cross-lane ops: structurally a float4 copy (the 6.3 TB/s pattern).

#define BLOCK 256
#define C_VEC 1024            // 4096 floats per row / 4 floats per float4
#define VPT 4                 // float4 per thread (1024 / 256)
#define MS4 1024              // 4096 assignment ints / 4 per int4
#define APT 4                 // int4 per thread (1024 / 256)
#define RANGE 64              // rows (bins) handled per count block
#define NROWS 4096

__global__ __launch_bounds__(BLOCK) void count_kernel(
    const int4* __restrict__ a4,
    float* __restrict__ scale) {
    __shared__ int bins[RANGE];
    const int tid = threadIdx.x;
    const int b0 = blockIdx.x * RANGE;

    if (tid < RANGE) bins[tid] = 0;
    __syncthreads();

    // Scan all 4096 assignments; count those landing in [b0, b0+RANGE).
#pragma unroll
    for (int k = 0; k < APT; ++k) {
        const int4 a = a4[tid + BLOCK * k];
        int d;
        d = a.x - b0; if ((unsigned)d < RANGE) atomicAdd(&bins[d], 1);
        d = a.y - b0; if ((unsigned)d < RANGE) atomicAdd(&bins[d], 1);
        d = a.z - b0; if ((unsigned)d < RANGE) atomicAdd(&bins[d], 1);
        d = a.w - b0; if ((unsigned)d < RANGE) atomicAdd(&bins[d], 1);
    }
    __syncthreads();

    if (tid < RANGE) scale[b0 + tid] = (float)bins[tid];
}

__global__ __launch_bounds__(BLOCK) void scale_kernel(
    const float4* __restrict__ x,
    const float* __restrict__ scale,
    float4* __restrict__ out) {
    const int b = blockIdx.x;
    const long base = (long)b * C_VEC + threadIdx.x;

    // Issue the row loads first so they are in flight under the scale load.
    float4 v[VPT];
#pragma unroll
    for (int k = 0; k < VPT; ++k)
        v[k] = x[base + BLOCK * k];

    // Uniform address -> scalar/broadcast load, one L2 line per block.
    const float s = scale[b];

#pragma unroll
    for (int k = 0; k < VPT; ++k) {
        float4 w = v[k];
        w.x *= s; w.y *= s; w.z *= s; w.w *= s;
        out[base + BLOCK * k] = w;
    }
}

extern "C" void kernel_launch(void* const* d_in, const int* in_sizes, int n_in,
                              void* d_out, int out_size, void* d_ws, size_t ws_size,
                              hipStream_t stream) {
    const float* x = (const float*)d_in[0];
    const int* assignments = (const int*)d_in[1];
    float* out = (float*)d_out;
    float* scale = (float*)d_ws;  // 16 KB of workspace

    count_kernel<<<dim3(NROWS / RANGE), dim3(BLOCK), 0, stream>>>(
        (const int4*)assignments, scale);
    scale_kernel<<<dim3(NROWS), dim3(BLOCK), 0, stream>>>(
        (const float4*)x, scale, (float4*)out);
}

// Round 2
// 112.532 us; speedup vs baseline: 1.0078x; 1.0078x over previous
//
#include <hip/hip_runtime.h>

// Problem constants: B=4096 rows, C=4096 channels, M*S=4096 assignment slots.
// Algebraic collapse of the reference:
//   out[b,c] = count[b] * x[b,c],  count[b] = #{(m,s): assignments[m,s]==b}
//   (padding -1 never matches a row index >= 0)
//
// Single fused dispatch (round-1 showed an extra dispatch costs ~3 us and the
// count phase is fully hidden under the HBM stream). This version amortizes
// the per-block overheads (16 KB L2 assignment scan, shuffle+LDS reduce, two
// barriers) over TWO rows per block:
//   - 2048 blocks x 256 threads = exactly 8 blocks/CU on 256 CUs, one full
//     resident pass, no tail.
//   - one scan produces both counts packed in one int (lo16/hi16; max count
//     4096 < 2^16, no overflow), one packed shuffle-reduce.
//   - 32 KB streamed per block instead of 16 KB.

#define BLOCK 256
#define C_VEC 1024            // 4096 floats per row / 4 per float4
#define VPT 4                 // float4 per thread per row (1024 / 256)
#define APT 4                 // int4 per thread over 4096 assignments
#define NROWS 4096
#define RPB 2                 // rows per block

__global__ __launch_bounds__(BLOCK) void mux_fused2(
    const float4* __restrict__ x,
    const int4* __restrict__ a4,
    float4* __restrict__ out) {
    const int tid = threadIdx.x;
    const int b0 = blockIdx.x * RPB;
    const int b1 = b0 + 1;

    // 1) issue both rows' loads early so they fly under the count/reduce
    const long base = (long)b0 * C_VEC + tid;
    float4 v0[VPT], v1[VPT];
#pragma unroll
    for (int k = 0; k < VPT; ++k) v0[k] = x[base + BLOCK * k];
#pragma unroll
    for (int k = 0; k < VPT; ++k) v1[k] = x[base + C_VEC + BLOCK * k];

    // 2) one scan of the 16 KB assignments (L2-broadcast), both counts packed
    int local = 0;
#pragma unroll
    for (int k = 0; k < APT; ++k) {
        const int4 a = a4[tid + BLOCK * k];
        local += (a.x == b0) + (a.y == b0) + (a.z == b0) + (a.w == b0);
        local += ((a.x == b1) + (a.y == b1) + (a.z == b1) + (a.w == b1)) << 16;
    }

    // 3) packed wave shuffle-reduce (width 64) then cross-wave LDS reduce
#pragma unroll
    for (int off = 32; off > 0; off >>= 1)
        local += __shfl_down(local, off, 64);

    __shared__ int wave_sum[BLOCK / 64];
    __shared__ float s_scale[RPB];
    const int wave = tid >> 6;
    if ((tid & 63) == 0) wave_sum[wave] = local;
    __syncthreads();
    if (tid == 0) {
        const int t = wave_sum[0] + wave_sum[1] + wave_sum[2] + wave_sum[3];
        s_scale[0] = (float)(t & 0xffff);
        s_scale[1] = (float)((unsigned)t >> 16);
    }
    __syncthreads();
    const float s0 = s_scale[0];
    const float s1 = s_scale[1];

    // 4) scale + store both rows
#pragma unroll
    for (int k = 0; k < VPT; ++k) {
        float4 w = v0[k];
        w.x *= s0; w.y *= s0; w.z *= s0; w.w *= s0;
        out[base + BLOCK * k] = w;
    }
#pragma unroll
    for (int k = 0; k < VPT; ++k) {
        float4 w = v1[k];
        w.x *= s1; w.y *= s1; w.z *= s1; w.w *= s1;
        out[base + C_VEC + BLOCK * k] = w;
    }
}

extern "C" void kernel_launch(void* const* d_in, const int* in_sizes, int n_in,
                              void* d_out, int out_size, void* d_ws, size_t ws_size,
                              hipStream_t stream) {
    const float* x = (const float*)d_in[0];
    const int* assignments = (const int*)d_in[1];
    float* out = (float*)d_out;

    mux_fused2<<<dim3(NROWS / RPB), dim3(BLOCK), 0, stream>>>(
        (const float4*)x, (const int4*)assignments, (float4*)out);
}